// Round 1
// baseline (126.998 us; speedup 1.0000x reference)
//
#include <hip/hip_runtime.h>

typedef float  f32x4  __attribute__((ext_vector_type(4)));
typedef __bf16 bf16x8 __attribute__((ext_vector_type(8)));
typedef unsigned int u32x4 __attribute__((ext_vector_type(4)));

#define CC 384
#define HH 64

__device__ __forceinline__ unsigned short f2bf(float f) {
  union { float f; unsigned int u; } x; x.f = f;
  unsigned int u = x.u;
  return (unsigned short)((u + 0x7fffu + ((u >> 16) & 1u)) >> 16);
}

__device__ __forceinline__ f32x4 mfma16(bf16x8 a, bf16x8 b, f32x4 c) {
  return __builtin_amdgcn_mfma_f32_16x16x32_bf16(a, b, c, 0, 0, 0);
}

// ---------------- kernel 0: repack W into B-fragment layout ----------------
// dst layout: [kk(0..11)][nt(0..11)][lane(0..63)][j(0..7)] bf16
// element (k, n):  kk=k>>5, lane=((k>>3)&3)*16 + (n&15), j=k&7, nt=n>>4
__global__ void repack_w(const float* __restrict__ Wq, const float* __restrict__ Wk,
                         const float* __restrict__ Wv, unsigned short* __restrict__ wf) {
  int e = blockIdx.x * 512 + threadIdx.x;      // 73728 total, exact
  int k = e / 192;
  int n = e - k * 192;
  const float* W = (n < 64) ? Wq : (n < 128) ? Wk : Wv;
  float val = W[k * 64 + (n & 63)];
  int kk = k >> 5;
  int lane = (((k >> 3) & 3) << 4) | (n & 15);
  int j = k & 7;
  int nt = n >> 4;
  wf[(size_t)(((kk * 12 + nt) << 6) + lane) * 8 + j] = f2bf(val);
}

// ---------------- kernel 1: QKV projection GEMM ----------------
// grid 1024 x 512 threads. Block covers 128 M-rows; wave w -> 16 rows, all 12 n-tiles.
__global__ void qkv_gemm(const float* __restrict__ x, const unsigned short* __restrict__ wf,
                         unsigned short* __restrict__ qw, unsigned short* __restrict__ kw,
                         unsigned short* __restrict__ vw) {
  __shared__ u32x4 lw[1536];  // 24KB: 2 k-steps x 12 frags x 64 lanes x 16B
  const int tid = threadIdx.x;
  const int w = tid >> 6, lane = tid & 63;
  const int l15 = lane & 15, lhi = lane >> 4;
  const size_t blockM = (size_t)blockIdx.x * 128;
  const int rowA = (int)blockM + w * 16 + l15;
  const float* xA = x + (size_t)rowA * CC + lhi * 8;

  f32x4 zero = {0.f, 0.f, 0.f, 0.f};
  f32x4 acc[12];
#pragma unroll
  for (int i = 0; i < 12; ++i) acc[i] = zero;

  for (int kp = 0; kp < 6; ++kp) {
    __syncthreads();
    const u32x4* src = (const u32x4*)wf + (size_t)kp * 1536;
#pragma unroll
    for (int i = 0; i < 3; ++i) lw[tid + i * 512] = src[tid + i * 512];
    __syncthreads();
#pragma unroll
    for (int k2 = 0; k2 < 2; ++k2) {
      const int ks = kp * 2 + k2;
      const float* ap = xA + ks * 32;
      f32x4 a0 = *(const f32x4*)(ap);
      f32x4 a1 = *(const f32x4*)(ap + 4);
      bf16x8 af;
      af[0] = (__bf16)a0[0]; af[1] = (__bf16)a0[1]; af[2] = (__bf16)a0[2]; af[3] = (__bf16)a0[3];
      af[4] = (__bf16)a1[0]; af[5] = (__bf16)a1[1]; af[6] = (__bf16)a1[2]; af[7] = (__bf16)a1[3];
      const bf16x8* bp = (const bf16x8*)((const unsigned short*)lw + k2 * 6144) + lane;
#pragma unroll
      for (int nt = 0; nt < 12; ++nt) acc[nt] = mfma16(af, bp[nt * 64], acc[nt]);
    }
  }
  // epilogue: n-tiles 0-3 -> q (pre-scaled), 4-7 -> k, 8-11 -> v (transposed [b][h][t])
  const float qs = 0.05103103630798288f;  // 384^-0.5
  const int rbase = (int)blockM + w * 16 + lhi * 4;
  const int bb = rbase >> 8;
  const int tt = rbase & 255;
#pragma unroll
  for (int nt = 0; nt < 12; ++nt) {
    const int h = ((nt & 3) << 4) + l15;
    if (nt < 4) {
#pragma unroll
      for (int r = 0; r < 4; ++r) qw[(size_t)(rbase + r) * HH + h] = f2bf(acc[nt][r] * qs);
    } else if (nt < 8) {
#pragma unroll
      for (int r = 0; r < 4; ++r) kw[(size_t)(rbase + r) * HH + h] = f2bf(acc[nt][r]);
    } else {
      unsigned long long pk =
          (unsigned long long)f2bf(acc[nt][0]) |
          ((unsigned long long)f2bf(acc[nt][1]) << 16) |
          ((unsigned long long)f2bf(acc[nt][2]) << 32) |
          ((unsigned long long)f2bf(acc[nt][3]) << 48);
      *(unsigned long long*)(vw + ((size_t)(bb * 64 + h) * 256 + tt)) = pk;
    }
  }
}

// ---------------- kernel 2: attention with column softmax ----------------
// one block per batch; 8 waves; wave w owns m-tiles {w, 15-w}
__global__ void attn(const unsigned short* __restrict__ qw, const unsigned short* __restrict__ kw,
                     const unsigned short* __restrict__ vw, float* __restrict__ out) {
  __shared__ float S[256 * 68];     // stride 68 -> conflict-light, 16B aligned rows
  __shared__ float pmax[8 * 64];
  __shared__ float psum[8 * 64];
  __shared__ float mcol[64];
  __shared__ float rinv[64];
  const int b = blockIdx.x;
  const int tid = threadIdx.x;
  const int w = tid >> 6, lane = tid & 63;
  const int l15 = lane & 15, lhi = lane >> 4;
  const int mts[2] = {w, 15 - w};
  const size_t qkbase = (size_t)b * 256 * 64;

  bf16x8 qf[2][2];
#pragma unroll
  for (int i = 0; i < 2; ++i)
#pragma unroll
    for (int kk = 0; kk < 2; ++kk)
      qf[i][kk] = *(const bf16x8*)(qw + qkbase + (size_t)(mts[i] * 16 + l15) * 64 + kk * 32 + lhi * 8);

  f32x4 zero = {0.f, 0.f, 0.f, 0.f};
  f32x4 acc[2][4];
#pragma unroll
  for (int i = 0; i < 2; ++i)
#pragma unroll
    for (int nh = 0; nh < 4; ++nh) acc[i][nh] = zero;

  for (int p = 0; p < 4; ++p) {
    const bool any = (mts[1] >= 4 * p);
    // ---- S compute ----
    if (any) {
      bf16x8 kf[4][2];
#pragma unroll
      for (int c = 0; c < 4; ++c)
#pragma unroll
        for (int kk = 0; kk < 2; ++kk)
          kf[c][kk] = *(const bf16x8*)(kw + qkbase + (size_t)(p * 64 + c * 16 + l15) * 64 + kk * 32 + lhi * 8);
#pragma unroll
      for (int i = 0; i < 2; ++i) {
        const int mt = mts[i];
        if (mt < 4 * p) continue;
        const int cmax = mt - 4 * p;
        const int rowb = mt * 16 + lhi * 4;
#pragma unroll
        for (int c = 0; c < 4; ++c) {
          if (c <= cmax) {
            f32x4 s = zero;
            s = mfma16(qf[i][0], kf[c][0], s);
            s = mfma16(qf[i][1], kf[c][1], s);
            float* dst = &S[rowb * 68 + c * 16 + l15];
#pragma unroll
            for (int r = 0; r < 4; ++r) dst[r * 68] = s[r];
          }
        }
      }
    }
    __syncthreads();  // B1
    // ---- column stats: lane -> cols [l15*4,+4), rows w*32 + lhi*8 .. +8 ----
    {
      const int cl = l15, rg = lhi;
      const int colg0 = p * 64 + cl * 4;
      f32x4 vals[8];
      float m0 = -1e30f, m1 = -1e30f, m2 = -1e30f, m3 = -1e30f;
#pragma unroll
      for (int rI = 0; rI < 8; ++rI) {
        const int row = w * 32 + rg * 8 + rI;
        f32x4 sv = *(const f32x4*)&S[row * 68 + cl * 4];
        sv[0] = (row >= colg0 + 0) ? sv[0] : -1e30f;
        sv[1] = (row >= colg0 + 1) ? sv[1] : -1e30f;
        sv[2] = (row >= colg0 + 2) ? sv[2] : -1e30f;
        sv[3] = (row >= colg0 + 3) ? sv[3] : -1e30f;
        vals[rI] = sv;
        m0 = fmaxf(m0, sv[0]); m1 = fmaxf(m1, sv[1]);
        m2 = fmaxf(m2, sv[2]); m3 = fmaxf(m3, sv[3]);
      }
      float s0 = 0.f, s1 = 0.f, s2 = 0.f, s3 = 0.f;
#pragma unroll
      for (int rI = 0; rI < 8; ++rI) {
        s0 += __expf(vals[rI][0] - m0);
        s1 += __expf(vals[rI][1] - m1);
        s2 += __expf(vals[rI][2] - m2);
        s3 += __expf(vals[rI][3] - m3);
      }
#pragma unroll
      for (int msk = 16; msk <= 32; msk <<= 1) {
        float om0 = __shfl_xor(m0, msk), os0 = __shfl_xor(s0, msk);
        float om1 = __shfl_xor(m1, msk), os1 = __shfl_xor(s1, msk);
        float om2 = __shfl_xor(m2, msk), os2 = __shfl_xor(s2, msk);
        float om3 = __shfl_xor(m3, msk), os3 = __shfl_xor(s3, msk);
        float nm;
        nm = fmaxf(m0, om0); s0 = s0 * __expf(m0 - nm) + os0 * __expf(om0 - nm); m0 = nm;
        nm = fmaxf(m1, om1); s1 = s1 * __expf(m1 - nm) + os1 * __expf(om1 - nm); m1 = nm;
        nm = fmaxf(m2, om2); s2 = s2 * __expf(m2 - nm) + os2 * __expf(om2 - nm); m2 = nm;
        nm = fmaxf(m3, om3); s3 = s3 * __expf(m3 - nm) + os3 * __expf(om3 - nm); m3 = nm;
      }
      if (rg == 0) {
        f32x4 pm; pm[0] = m0; pm[1] = m1; pm[2] = m2; pm[3] = m3;
        f32x4 ps; ps[0] = s0; ps[1] = s1; ps[2] = s2; ps[3] = s3;
        *(f32x4*)&pmax[w * 64 + cl * 4] = pm;
        *(f32x4*)&psum[w * 64 + cl * 4] = ps;
      }
    }
    __syncthreads();  // B2
    if (w == 0) {
      float M = -1e30f;
#pragma unroll
      for (int g = 0; g < 8; ++g) M = fmaxf(M, pmax[g * 64 + lane]);
      float L = 0.f;
#pragma unroll
      for (int g = 0; g < 8; ++g) L += psum[g * 64 + lane] * __expf(pmax[g * 64 + lane] - M);
      mcol[lane] = M;
      rinv[lane] = 1.0f / L;
    }
    __syncthreads();  // B3
    // ---- W = exp(S-m)*rinv, PV accumulate ----
    if (any) {
      bf16x8 vf[4][2];
#pragma unroll
      for (int nh = 0; nh < 4; ++nh)
#pragma unroll
        for (int kk = 0; kk < 2; ++kk)
          vf[nh][kk] = *(const bf16x8*)(vw + (size_t)(b * 64 + nh * 16 + l15) * 256 + p * 64 + kk * 32 + lhi * 8);
#pragma unroll
      for (int i = 0; i < 2; ++i) {
        const int mt = mts[i];
        if (mt < 4 * p) continue;
        const int grow = mt * 16 + l15;
        const int dmax = mt - 4 * p;
#pragma unroll
        for (int kk = 0; kk < 2; ++kk) {
          if (kk == 1 && dmax <= 1) continue;  // whole upper half masked
          const int c0 = kk * 32 + lhi * 8;
          f32x4 sA = *(const f32x4*)&S[grow * 68 + c0];
          f32x4 sB = *(const f32x4*)&S[grow * 68 + c0 + 4];
          f32x4 mA = *(const f32x4*)&mcol[c0];
          f32x4 mB = *(const f32x4*)&mcol[c0 + 4];
          f32x4 rA = *(const f32x4*)&rinv[c0];
          f32x4 rB = *(const f32x4*)&rinv[c0 + 4];
          const int cg0 = p * 64 + c0;
          bf16x8 wfr;
#pragma unroll
          for (int j = 0; j < 4; ++j) {
            float wv = (cg0 + j <= grow) ? __expf(sA[j] - mA[j]) * rA[j] : 0.f;
            wfr[j] = (__bf16)wv;
          }
#pragma unroll
          for (int j = 0; j < 4; ++j) {
            float wv = (cg0 + 4 + j <= grow) ? __expf(sB[j] - mB[j]) * rB[j] : 0.f;
            wfr[4 + j] = (__bf16)wv;
          }
#pragma unroll
          for (int nh = 0; nh < 4; ++nh) acc[i][nh] = mfma16(wfr, vf[nh][kk], acc[i][nh]);
        }
      }
    }
    // no extra barrier: next phase's S writes touch only the writer wave's own rows
  }
  // ---- epilogue ----
#pragma unroll
  for (int i = 0; i < 2; ++i) {
    const int rb = mts[i] * 16 + lhi * 4;
#pragma unroll
    for (int nh = 0; nh < 4; ++nh) {
      const int h = nh * 16 + l15;
#pragma unroll
      for (int r = 0; r < 4; ++r)
        out[(size_t)b * 16384 + (size_t)(rb + r) * 64 + h] = acc[i][nh][r];
    }
  }
}

extern "C" void kernel_launch(void* const* d_in, const int* in_sizes, int n_in,
                              void* d_out, int out_size, void* d_ws, size_t ws_size,
                              hipStream_t stream) {
  const float* x  = (const float*)d_in[0];
  const float* Wq = (const float*)d_in[1];
  const float* Wk = (const float*)d_in[2];
  const float* Wv = (const float*)d_in[3];
  float* out = (float*)d_out;

  unsigned short* qw = (unsigned short*)d_ws;              // [131072][64] bf16
  unsigned short* kw = qw + (size_t)131072 * 64;           // [131072][64] bf16
  unsigned short* vw = kw + (size_t)131072 * 64;           // [512][64][256] bf16
  unsigned short* wf = vw + (size_t)131072 * 64;           // 73728 bf16 frag-packed

  repack_w<<<144, 512, 0, stream>>>(Wq, Wk, Wv, wf);
  qkv_gemm<<<1024, 512, 0, stream>>>(x, wf, qw, kw, vw);
  attn<<<512, 512, 0, stream>>>(qw, kw, vw, out);
}

// Round 2
// 111.338 us; speedup vs baseline: 1.1407x; 1.1407x over previous
//
#include <hip/hip_runtime.h>

typedef float  f32x4  __attribute__((ext_vector_type(4)));
typedef __bf16 bf16x8 __attribute__((ext_vector_type(8)));

#define CC 384
#define HH 64

__device__ __forceinline__ unsigned short f2bf(float f) {
  union { float f; unsigned int u; } x; x.f = f;
  unsigned int u = x.u;
  return (unsigned short)((u + 0x7fffu + ((u >> 16) & 1u)) >> 16);
}

__device__ __forceinline__ f32x4 mfma16(bf16x8 a, bf16x8 b, f32x4 c) {
  return __builtin_amdgcn_mfma_f32_16x16x32_bf16(a, b, c, 0, 0, 0);
}

// ---------------- kernel 0: repack W into B-fragment layout ----------------
// dst: [kk(0..11)][nt(0..11)][lane(0..63)][j(0..7)] bf16
// element (k, n): kk=k>>5, lane=((k>>3)&3)*16 + (n&15), j=k&7, nt=n>>4
__global__ void repack_w(const float* __restrict__ Wq, const float* __restrict__ Wk,
                         const float* __restrict__ Wv, unsigned short* __restrict__ wf) {
  int e = blockIdx.x * 512 + threadIdx.x;      // 73728 total, exact
  int k = e / 192;
  int n = e - k * 192;
  const float* W = (n < 64) ? Wq : (n < 128) ? Wk : Wv;
  float val = W[k * 64 + (n & 63)];
  int kk = k >> 5;
  int lane = (((k >> 3) & 3) << 4) | (n & 15);
  int j = k & 7;
  int nt = n >> 4;
  wf[(size_t)(((kk * 12 + nt) << 6) + lane) * 8 + j] = f2bf(val);
}

// ---------------- kernel 1: QKV projection GEMM (dbuf + glds + prefetch) ----------------
// grid 1024 x 512 threads; block = 128 M-rows; wave w -> 16 rows, all 12 n-tiles.
__global__ void qkv_gemm(const float* __restrict__ x, const unsigned short* __restrict__ wf,
                         unsigned short* __restrict__ qw, unsigned short* __restrict__ kw,
                         unsigned short* __restrict__ vw) {
  __shared__ unsigned short lw[2][12288];  // 2 x 24KB W-tile double buffer
  const int tid = threadIdx.x;
  const int w = tid >> 6, lane = tid & 63;
  const int l15 = lane & 15, lhi = lane >> 4;
  const size_t blockM = (size_t)blockIdx.x * 128;
  const int rowA = (int)blockM + w * 16 + l15;
  const float* xA = x + (size_t)rowA * CC + lhi * 8;

  f32x4 zero = {0.f, 0.f, 0.f, 0.f};
  f32x4 acc[12];
#pragma unroll
  for (int i = 0; i < 12; ++i) acc[i] = zero;

  // async-stage phase kp's 24KB W tile into buffer b (lane-linear, 16B per lane)
#define STAGE(kp_, b_) do {                                                          \
    const unsigned short* s_ = wf + (size_t)(kp_) * 12288 + tid * 8;                 \
    unsigned short* d_ = &lw[(b_)][tid * 8];                                         \
    __builtin_amdgcn_global_load_lds((const __attribute__((address_space(1))) void*)(s_),        \
                                     (__attribute__((address_space(3))) void*)(d_), 16, 0, 0);   \
    __builtin_amdgcn_global_load_lds((const __attribute__((address_space(1))) void*)(s_ + 4096), \
                                     (__attribute__((address_space(3))) void*)(d_ + 4096), 16, 0, 0); \
    __builtin_amdgcn_global_load_lds((const __attribute__((address_space(1))) void*)(s_ + 8192), \
                                     (__attribute__((address_space(3))) void*)(d_ + 8192), 16, 0, 0); \
  } while (0)

  STAGE(0, 0);
  f32x4 aC0 = *(const f32x4*)(xA + 0);
  f32x4 aC1 = *(const f32x4*)(xA + 4);
  f32x4 aC2 = *(const f32x4*)(xA + 32);
  f32x4 aC3 = *(const f32x4*)(xA + 36);

  for (int kp = 0; kp < 6; ++kp) {
    __syncthreads();  // vmcnt(0) drain before barrier => buf[kp&1] staged, prev reads done
    f32x4 aN0 = zero, aN1 = zero, aN2 = zero, aN3 = zero;
    if (kp < 5) {
      STAGE(kp + 1, (kp + 1) & 1);
      const float* nx = xA + (kp + 1) * 64;
      aN0 = *(const f32x4*)(nx);
      aN1 = *(const f32x4*)(nx + 4);
      aN2 = *(const f32x4*)(nx + 32);
      aN3 = *(const f32x4*)(nx + 36);
    }
    const unsigned short* base = lw[kp & 1];
#pragma unroll
    for (int k2 = 0; k2 < 2; ++k2) {
      f32x4 lo = k2 ? aC2 : aC0;
      f32x4 hi = k2 ? aC3 : aC1;
      bf16x8 af;
      af[0] = (__bf16)lo[0]; af[1] = (__bf16)lo[1]; af[2] = (__bf16)lo[2]; af[3] = (__bf16)lo[3];
      af[4] = (__bf16)hi[0]; af[5] = (__bf16)hi[1]; af[6] = (__bf16)hi[2]; af[7] = (__bf16)hi[3];
      const bf16x8* bp = (const bf16x8*)(base + k2 * 6144) + lane;
#pragma unroll
      for (int nt = 0; nt < 12; ++nt) acc[nt] = mfma16(af, bp[nt * 64], acc[nt]);
    }
    aC0 = aN0; aC1 = aN1; aC2 = aN2; aC3 = aN3;
  }
#undef STAGE

  // epilogue: n-tiles 0-3 -> q (pre-scaled), 4-7 -> k, 8-11 -> v (transposed [b][h][t])
  const float qs = 0.05103103630798288f;  // 384^-0.5
  const int rbase = (int)blockM + w * 16 + lhi * 4;
  const int bb = rbase >> 8;
  const int tt = rbase & 255;
#pragma unroll
  for (int nt = 0; nt < 12; ++nt) {
    const int h = ((nt & 3) << 4) + l15;
    if (nt < 4) {
#pragma unroll
      for (int r = 0; r < 4; ++r) qw[(size_t)(rbase + r) * HH + h] = f2bf(acc[nt][r] * qs);
    } else if (nt < 8) {
#pragma unroll
      for (int r = 0; r < 4; ++r) kw[(size_t)(rbase + r) * HH + h] = f2bf(acc[nt][r]);
    } else {
      unsigned long long pk =
          (unsigned long long)f2bf(acc[nt][0]) |
          ((unsigned long long)f2bf(acc[nt][1]) << 16) |
          ((unsigned long long)f2bf(acc[nt][2]) << 32) |
          ((unsigned long long)f2bf(acc[nt][3]) << 48);
      *(unsigned long long*)(vw + ((size_t)(bb * 64 + h) * 256 + tt)) = pk;
    }
  }
}

// ---------------- kernel 2: attention, column softmax, in-register stats ----------------
// one block per batch; 8 waves; wave w owns m-tiles {w, 15-w}
__global__ void attn(const unsigned short* __restrict__ qw, const unsigned short* __restrict__ kw,
                     const unsigned short* __restrict__ vw, float* __restrict__ out) {
  __shared__ unsigned short Sx[256][72];  // exp(S - m_tile) bf16; 144B rows (16B aligned)
  __shared__ float pm[16][64];            // per (m-tile, col) partial max
  __shared__ float ps[16][64];            // per (m-tile, col) partial sumexp
  __shared__ float gg[16][64];            // per (m-tile, col) scale exp(pm-M)/L
  const int b = blockIdx.x;
  const int tid = threadIdx.x;
  const int w = tid >> 6, lane = tid & 63;
  const int l15 = lane & 15, lhi = lane >> 4;
  const int mts[2] = {w, 15 - w};
  const size_t qkbase = (size_t)b * 256 * 64;

  bf16x8 qf[2][2];
#pragma unroll
  for (int i = 0; i < 2; ++i)
#pragma unroll
    for (int kk = 0; kk < 2; ++kk)
      qf[i][kk] = *(const bf16x8*)(qw + qkbase + (size_t)(mts[i] * 16 + l15) * 64 + kk * 32 + lhi * 8);

  f32x4 zero = {0.f, 0.f, 0.f, 0.f};
  f32x4 acc[2][4];
#pragma unroll
  for (int i = 0; i < 2; ++i)
#pragma unroll
    for (int nh = 0; nh < 4; ++nh) acc[i][nh] = zero;

  for (int p = 0; p < 4; ++p) {
    const int p4 = 4 * p;
    const bool any = (mts[1] >= p4);
    // ---- S compute + in-register column stats + exp write ----
    if (any) {
      bf16x8 kf[4][2];
#pragma unroll
      for (int c = 0; c < 4; ++c)
#pragma unroll
        for (int kk = 0; kk < 2; ++kk)
          kf[c][kk] = *(const bf16x8*)(kw + qkbase + (size_t)(p * 64 + c * 16 + l15) * 64 + kk * 32 + lhi * 8);
#pragma unroll
      for (int i = 0; i < 2; ++i) {
        const int mt = mts[i];
        if (mt < p4) continue;
        const int cmax = mt - p4;
        const int rowb = mt * 16 + lhi * 4;
#pragma unroll
        for (int c = 0; c < 4; ++c) {
          const int cs = c * 16 + l15;  // col within stripe
          if (c <= cmax) {
            f32x4 s = zero;
            s = mfma16(qf[i][0], kf[c][0], s);
            s = mfma16(qf[i][1], kf[c][1], s);
            const int cg = p * 64 + cs;  // global col
            const bool v0 = (rowb + 0) >= cg, v1 = (rowb + 1) >= cg;
            const bool v2 = (rowb + 2) >= cg, v3 = (rowb + 3) >= cg;
            float m = -1e30f;
            m = fmaxf(m, v0 ? s[0] : -1e30f);
            m = fmaxf(m, v1 ? s[1] : -1e30f);
            m = fmaxf(m, v2 ? s[2] : -1e30f);
            m = fmaxf(m, v3 ? s[3] : -1e30f);
            m = fmaxf(m, __shfl_xor(m, 16));
            m = fmaxf(m, __shfl_xor(m, 32));   // tile-column max over 16 rows
            const float e0 = v0 ? __expf(s[0] - m) : 0.f;
            const float e1 = v1 ? __expf(s[1] - m) : 0.f;
            const float e2 = v2 ? __expf(s[2] - m) : 0.f;
            const float e3 = v3 ? __expf(s[3] - m) : 0.f;
            float t = e0 + e1 + e2 + e3;
            t += __shfl_xor(t, 16);
            t += __shfl_xor(t, 32);            // tile-column sumexp
            Sx[rowb + 0][cs] = f2bf(e0);
            Sx[rowb + 1][cs] = f2bf(e1);
            Sx[rowb + 2][cs] = f2bf(e2);
            Sx[rowb + 3][cs] = f2bf(e3);
            if (lhi == 0) { pm[mt][cs] = m; ps[mt][cs] = t; }
          } else {
            if (lhi == 0) { pm[mt][cs] = -1e30f; ps[mt][cs] = 0.f; }
          }
        }
      }
    }
    __syncthreads();  // B1: pm/ps/Sx stripe complete
    // ---- per-column reduce (all waves redundant; each wave writes its g rows) ----
    {
      float M = -1e30f;
      for (int mt = p4; mt < 16; ++mt) M = fmaxf(M, pm[mt][lane]);
      float L = 0.f;
      for (int mt = p4; mt < 16; ++mt) L += ps[mt][lane] * __expf(pm[mt][lane] - M);
      const float rv = 1.0f / L;
      int mtw = p4 + w;
      if (mtw < 16) gg[mtw][lane] = __expf(pm[mtw][lane] - M) * rv;
      mtw += 8;
      if (mtw < 16) gg[mtw][lane] = __expf(pm[mtw][lane] - M) * rv;
    }
    __syncthreads();  // B2: g ready
    // ---- W = Sx * g (no exp), PV accumulate ----
    if (any) {
      bf16x8 vf[4][2];
#pragma unroll
      for (int nh = 0; nh < 4; ++nh)
#pragma unroll
        for (int kk = 0; kk < 2; ++kk)
          vf[nh][kk] = *(const bf16x8*)(vw + (size_t)(b * 64 + nh * 16 + l15) * 256 + p * 64 + kk * 32 + lhi * 8);
#pragma unroll
      for (int i = 0; i < 2; ++i) {
        const int mt = mts[i];
        if (mt < p4) continue;
        const int grow = mt * 16 + l15;
        const int dmax = mt - p4;
#pragma unroll
        for (int kk = 0; kk < 2; ++kk) {
          if (kk == 1 && dmax <= 1) continue;  // upper half fully masked
          const int c0 = kk * 32 + lhi * 8;
          bf16x8 se = *(const bf16x8*)&Sx[grow][c0];
          f32x4 gA = *(const f32x4*)&gg[mt][c0];
          f32x4 gB = *(const f32x4*)&gg[mt][c0 + 4];
          const int cg0 = p * 64 + c0;
          bf16x8 wfr;
#pragma unroll
          for (int j = 0; j < 4; ++j)
            wfr[j] = (cg0 + j <= grow) ? (__bf16)((float)se[j] * gA[j]) : (__bf16)0.f;
#pragma unroll
          for (int j = 0; j < 4; ++j)
            wfr[4 + j] = (cg0 + 4 + j <= grow) ? (__bf16)((float)se[4 + j] * gB[j]) : (__bf16)0.f;
#pragma unroll
          for (int nh = 0; nh < 4; ++nh) acc[i][nh] = mfma16(wfr, vf[nh][kk], acc[i][nh]);
        }
      }
    }
    // next phase's LDS writes are hazard-free: Sx rows are wave-private,
    // pm/ps writes happen after this phase's readers passed B2, g after B1(p+1).
  }
  // ---- epilogue ----
#pragma unroll
  for (int i = 0; i < 2; ++i) {
    const int rb = mts[i] * 16 + lhi * 4;
#pragma unroll
    for (int nh = 0; nh < 4; ++nh) {
      const int h = nh * 16 + l15;
#pragma unroll
      for (int r = 0; r < 4; ++r)
        out[(size_t)b * 16384 + (size_t)(rb + r) * 64 + h] = acc[i][nh][r];
    }
  }
}

extern "C" void kernel_launch(void* const* d_in, const int* in_sizes, int n_in,
                              void* d_out, int out_size, void* d_ws, size_t ws_size,
                              hipStream_t stream) {
  const float* x  = (const float*)d_in[0];
  const float* Wq = (const float*)d_in[1];
  const float* Wk = (const float*)d_in[2];
  const float* Wv = (const float*)d_in[3];
  float* out = (float*)d_out;

  unsigned short* qw = (unsigned short*)d_ws;              // [131072][64] bf16
  unsigned short* kw = qw + (size_t)131072 * 64;           // [131072][64] bf16
  unsigned short* vw = kw + (size_t)131072 * 64;           // [512][64][256] bf16
  unsigned short* wf = vw + (size_t)131072 * 64;           // 73728 bf16 frag-packed

  repack_w<<<144, 512, 0, stream>>>(Wq, Wk, Wv, wf);
  qkv_gemm<<<1024, 512, 0, stream>>>(x, wf, qw, kw, vw);
  attn<<<512, 512, 0, stream>>>(qw, kw, vw, out);
}

// Round 3
// 82.870 us; speedup vs baseline: 1.5325x; 1.3435x over previous
//
#include <hip/hip_runtime.h>

typedef float  f32x4  __attribute__((ext_vector_type(4)));
typedef __bf16 bf16x8 __attribute__((ext_vector_type(8)));

#define CC 384

__device__ __forceinline__ unsigned short f2bf(float f) {
  union { float f; unsigned int u; } x; x.f = f;
  unsigned int u = x.u;
  return (unsigned short)((u + 0x7fffu + ((u >> 16) & 1u)) >> 16);
}

__device__ __forceinline__ f32x4 mfma16(bf16x8 a, bf16x8 b, f32x4 c) {
  return __builtin_amdgcn_mfma_f32_16x16x32_bf16(a, b, c, 0, 0, 0);
}

// ---------------- kernel 0: repack W into B-fragment layout ----------------
// dst: [kk(0..11)][nt(0..11)][lane(0..63)][j(0..7)] bf16
// element (k, n): kk=k>>5, lane=((k>>3)&3)*16 + (n&15), j=k&7, nt=n>>4
__global__ void repack_w(const float* __restrict__ Wq, const float* __restrict__ Wk,
                         const float* __restrict__ Wv, unsigned short* __restrict__ wf) {
  int e = blockIdx.x * 512 + threadIdx.x;      // 73728 total, exact
  int k = e / 192;
  int n = e - k * 192;
  const float* W = (n < 64) ? Wq : (n < 128) ? Wk : Wv;
  float val = W[k * 64 + (n & 63)];
  int kk = k >> 5;
  int lane = (((k >> 3) & 3) << 4) | (n & 15);
  int j = k & 7;
  int nt = n >> 4;
  wf[(size_t)(((kk * 12 + nt) << 6) + lane) * 8 + j] = f2bf(val);
}

// ---------------- fused kernel: QKV projection + column-softmax attention ----------------
// one block per batch, 8 waves; wave w owns m-tiles {w, 15-w} (32 q-rows) for BOTH stages.
__global__ __launch_bounds__(512, 1) void fused(const float* __restrict__ x,
                                                const unsigned short* __restrict__ wf,
                                                float* __restrict__ out) {
  // LDS union layout (119,808 B total):
  //  [0, 36864)        Sx[256][72] bf16  == q-scratch == W-stage dbuf (2x12,288 B)
  //  [36864, 73728)    kL[256][72] bf16
  //  [73728, 107520)   vT[64][264] bf16
  //  [107520, 119808)  pm/ps/gg [16][64] f32 each
  __shared__ __attribute__((aligned(16))) unsigned char smem[119808];
  unsigned short (*Sx)[72] = (unsigned short(*)[72])smem;
  unsigned short (*kL)[72] = (unsigned short(*)[72])(smem + 36864);
  unsigned short (*vT)[264] = (unsigned short(*)[264])(smem + 73728);
  float* pm = (float*)(smem + 107520);
  float* ps = pm + 1024;
  float* gg = ps + 1024;
  unsigned short* wst = (unsigned short*)smem;   // W stage: 2 x 6144 shorts

  const int tid = threadIdx.x;
  const int w = tid >> 6, lane = tid & 63;
  const int l15 = lane & 15, lhi = lane >> 4;
  const int b = blockIdx.x;
  const int mts[2] = {w, 15 - w};

  // ================= projection =================
  const float* xr0 = x + ((size_t)b * 256 + mts[0] * 16 + l15) * CC + lhi * 8;
  const float* xr1 = x + ((size_t)b * 256 + mts[1] * 16 + l15) * CC + lhi * 8;

  f32x4 zero = {0.f, 0.f, 0.f, 0.f};
  f32x4 acc[2][12];
#pragma unroll
  for (int i = 0; i < 2; ++i)
#pragma unroll
    for (int nt = 0; nt < 12; ++nt) acc[i][nt] = zero;

  // stage 12,288-B W chunk for K=32 step kp into dbuf half b_
#define STAGE(kp_, b_) do {                                                                           \
    const unsigned short* s_ = wf + (size_t)(kp_) * 6144 + tid * 8;                                   \
    unsigned short* d_ = wst + (b_) * 6144 + tid * 8;                                                 \
    __builtin_amdgcn_global_load_lds((const __attribute__((address_space(1))) void*)(s_),             \
                                     (__attribute__((address_space(3))) void*)(d_), 16, 0, 0);        \
    if (tid < 256)                                                                                    \
      __builtin_amdgcn_global_load_lds((const __attribute__((address_space(1))) void*)(s_ + 4096),    \
                                       (__attribute__((address_space(3))) void*)(d_ + 4096), 16, 0, 0);\
  } while (0)

  STAGE(0, 0);
  f32x4 aC[2][2];
  aC[0][0] = *(const f32x4*)(xr0);     aC[0][1] = *(const f32x4*)(xr0 + 4);
  aC[1][0] = *(const f32x4*)(xr1);     aC[1][1] = *(const f32x4*)(xr1 + 4);

  for (int kp = 0; kp < 12; ++kp) {
    __syncthreads();  // drain: stage(kp) + current A in LDS/regs; buf[(kp-1)&1] readers done
    f32x4 aN[2][2];
#pragma unroll
    for (int i = 0; i < 2; ++i) { aN[i][0] = zero; aN[i][1] = zero; }
    if (kp < 11) {
      const int o = (kp + 1) * 32;
      aN[0][0] = *(const f32x4*)(xr0 + o);     aN[0][1] = *(const f32x4*)(xr0 + o + 4);
      aN[1][0] = *(const f32x4*)(xr1 + o);     aN[1][1] = *(const f32x4*)(xr1 + o + 4);
      STAGE(kp + 1, (kp + 1) & 1);
    }
    const bf16x8* bp = (const bf16x8*)(wst + (kp & 1) * 6144) + lane;
#pragma unroll
    for (int i = 0; i < 2; ++i) {
      bf16x8 af;
#pragma unroll
      for (int j = 0; j < 4; ++j) { af[j] = (__bf16)aC[i][0][j]; af[4 + j] = (__bf16)aC[i][1][j]; }
#pragma unroll
      for (int nt = 0; nt < 12; ++nt) acc[i][nt] = mfma16(af, bp[nt * 64], acc[i][nt]);
    }
#pragma unroll
    for (int i = 0; i < 2; ++i) { aC[i][0] = aN[i][0]; aC[i][1] = aN[i][1]; }
  }
#undef STAGE
  __syncthreads();  // all W-stage reads done; Sx region is now free for q-scratch

  // epilogue: q (scaled) -> Sx scratch, k -> kL, v -> vT (transposed, packed b64)
  const float qs = 0.05103103630798288f;  // 384^-0.5
#pragma unroll
  for (int i = 0; i < 2; ++i) {
    const int rb = mts[i] * 16 + lhi * 4;
#pragma unroll
    for (int nt = 0; nt < 4; ++nt) {
      const int h = nt * 16 + l15;
#pragma unroll
      for (int r = 0; r < 4; ++r) Sx[rb + r][h] = f2bf(acc[i][nt][r] * qs);
    }
#pragma unroll
    for (int nt = 4; nt < 8; ++nt) {
      const int h = (nt - 4) * 16 + l15;
#pragma unroll
      for (int r = 0; r < 4; ++r) kL[rb + r][h] = f2bf(acc[i][nt][r]);
    }
#pragma unroll
    for (int nt = 8; nt < 12; ++nt) {
      const int h = (nt - 8) * 16 + l15;
      unsigned long long pk =
          (unsigned long long)f2bf(acc[i][nt][0]) |
          ((unsigned long long)f2bf(acc[i][nt][1]) << 16) |
          ((unsigned long long)f2bf(acc[i][nt][2]) << 32) |
          ((unsigned long long)f2bf(acc[i][nt][3]) << 48);
      *(unsigned long long*)&vT[h][rb] = pk;
    }
  }
  __syncthreads();  // q/k/v LDS-resident

  // q fragments (reads own rows; later Sx overwrites of same rows are in-wave ordered)
  bf16x8 qf[2][2];
#pragma unroll
  for (int i = 0; i < 2; ++i)
#pragma unroll
    for (int kk = 0; kk < 2; ++kk)
      qf[i][kk] = *(const bf16x8*)&Sx[mts[i] * 16 + l15][kk * 32 + lhi * 8];

  // ================= attention =================
  f32x4 oacc[2][4];
#pragma unroll
  for (int i = 0; i < 2; ++i)
#pragma unroll
    for (int nh = 0; nh < 4; ++nh) oacc[i][nh] = zero;

  for (int p = 0; p < 4; ++p) {
    const int p4 = 4 * p;
    const bool any = (mts[1] >= p4);
    // ---- S compute + in-register tile-column stats + exp write ----
    if (any) {
      bf16x8 kf[4][2];
#pragma unroll
      for (int c = 0; c < 4; ++c)
#pragma unroll
        for (int kk = 0; kk < 2; ++kk)
          kf[c][kk] = *(const bf16x8*)&kL[p * 64 + c * 16 + l15][kk * 32 + lhi * 8];
#pragma unroll
      for (int i = 0; i < 2; ++i) {
        const int mt = mts[i];
        if (mt < p4) continue;
        const int cmax = mt - p4;
        const int rowb = mt * 16 + lhi * 4;
#pragma unroll
        for (int c = 0; c < 4; ++c) {
          const int cs = c * 16 + l15;
          if (c <= cmax) {
            f32x4 s = zero;
            s = mfma16(qf[i][0], kf[c][0], s);
            s = mfma16(qf[i][1], kf[c][1], s);
            const int cg = p * 64 + cs;
            const bool v0 = (rowb + 0) >= cg, v1 = (rowb + 1) >= cg;
            const bool v2 = (rowb + 2) >= cg, v3 = (rowb + 3) >= cg;
            float m = -1e30f;
            m = fmaxf(m, v0 ? s[0] : -1e30f);
            m = fmaxf(m, v1 ? s[1] : -1e30f);
            m = fmaxf(m, v2 ? s[2] : -1e30f);
            m = fmaxf(m, v3 ? s[3] : -1e30f);
            m = fmaxf(m, __shfl_xor(m, 16));
            m = fmaxf(m, __shfl_xor(m, 32));
            const float e0 = v0 ? __expf(s[0] - m) : 0.f;
            const float e1 = v1 ? __expf(s[1] - m) : 0.f;
            const float e2 = v2 ? __expf(s[2] - m) : 0.f;
            const float e3 = v3 ? __expf(s[3] - m) : 0.f;
            float t = e0 + e1 + e2 + e3;
            t += __shfl_xor(t, 16);
            t += __shfl_xor(t, 32);
            Sx[rowb + 0][cs] = f2bf(e0);
            Sx[rowb + 1][cs] = f2bf(e1);
            Sx[rowb + 2][cs] = f2bf(e2);
            Sx[rowb + 3][cs] = f2bf(e3);
            if (lhi == 0) { pm[mt * 64 + cs] = m; ps[mt * 64 + cs] = t; }
          } else {
            if (lhi == 0) { pm[mt * 64 + cs] = -1e30f; ps[mt * 64 + cs] = 0.f; }
          }
        }
      }
    }
    __syncthreads();  // B1: pm/ps/Sx stripe complete
    // ---- per-column reduce (redundant across waves; each wave writes its gg rows) ----
    {
      float M = -1e30f;
      for (int mt = p4; mt < 16; ++mt) M = fmaxf(M, pm[mt * 64 + lane]);
      float L = 0.f;
      for (int mt = p4; mt < 16; ++mt) L += ps[mt * 64 + lane] * __expf(pm[mt * 64 + lane] - M);
      const float rv = 1.0f / L;
      int mtw = p4 + w;
      if (mtw < 16) gg[mtw * 64 + lane] = __expf(pm[mtw * 64 + lane] - M) * rv;
      mtw += 8;
      if (mtw < 16) gg[mtw * 64 + lane] = __expf(pm[mtw * 64 + lane] - M) * rv;
    }
    __syncthreads();  // B2: gg ready (also fences pm/ps readers vs next-phase writers)
    // ---- W = Sx * gg, PV accumulate ----
    if (any) {
      bf16x8 vf[4][2];
#pragma unroll
      for (int nh = 0; nh < 4; ++nh)
#pragma unroll
        for (int kk = 0; kk < 2; ++kk)
          vf[nh][kk] = *(const bf16x8*)&vT[nh * 16 + l15][p * 64 + kk * 32 + lhi * 8];
#pragma unroll
      for (int i = 0; i < 2; ++i) {
        const int mt = mts[i];
        if (mt < p4) continue;
        const int grow = mt * 16 + l15;
        const int dmax = mt - p4;
#pragma unroll
        for (int kk = 0; kk < 2; ++kk) {
          if (kk == 1 && dmax <= 1) continue;  // upper half fully masked
          const int c0 = kk * 32 + lhi * 8;
          bf16x8 se = *(const bf16x8*)&Sx[grow][c0];
          f32x4 gA = *(const f32x4*)&gg[mt * 64 + c0];
          f32x4 gB = *(const f32x4*)&gg[mt * 64 + c0 + 4];
          const int cg0 = p * 64 + c0;
          bf16x8 wfr;
#pragma unroll
          for (int j = 0; j < 4; ++j)
            wfr[j] = (cg0 + j <= grow) ? (__bf16)((float)se[j] * gA[j]) : (__bf16)0.f;
#pragma unroll
          for (int j = 0; j < 4; ++j)
            wfr[4 + j] = (cg0 + 4 + j <= grow) ? (__bf16)((float)se[4 + j] * gB[j]) : (__bf16)0.f;
#pragma unroll
          for (int nh = 0; nh < 4; ++nh) oacc[i][nh] = mfma16(wfr, vf[nh][kk], oacc[i][nh]);
        }
      }
    }
  }
  // ---- output ----
#pragma unroll
  for (int i = 0; i < 2; ++i) {
    const int rb = mts[i] * 16 + lhi * 4;
#pragma unroll
    for (int nh = 0; nh < 4; ++nh) {
      const int h = nh * 16 + l15;
#pragma unroll
      for (int r = 0; r < 4; ++r)
        out[(size_t)b * 16384 + (size_t)(rb + r) * 64 + h] = oacc[i][nh][r];
    }
  }
}

extern "C" void kernel_launch(void* const* d_in, const int* in_sizes, int n_in,
                              void* d_out, int out_size, void* d_ws, size_t ws_size,
                              hipStream_t stream) {
  const float* x  = (const float*)d_in[0];
  const float* Wq = (const float*)d_in[1];
  const float* Wk = (const float*)d_in[2];
  const float* Wv = (const float*)d_in[3];
  float* out = (float*)d_out;

  unsigned short* wf = (unsigned short*)d_ws;   // 73728 bf16 frag-packed W

  repack_w<<<144, 512, 0, stream>>>(Wq, Wk, Wv, wf);
  fused<<<512, 512, 0, stream>>>(x, wf, out);
}